// Round 1
// baseline (225.380 us; speedup 1.0000x reference)
//
#include <hip/hip_runtime.h>
#include <hip/hip_bf16.h>
#include <stdint.h>

// DelayedDMD: BS=64, D=256, M=512, m_prox=10 (fixed). A-orientation algebra:
//   G1 = Y1@Y1^T (sym), G21 = Y2@Y1^T
//   q = P^T y1, Piy1 = P y1, k = 1/(1+y1.Piy1)
//   w = y1 - G1 q ; u = G21 q
//   negE = -(P@G1 + k y1 w^T)  [bf16]
//   V'   = G21@P^T + k (y2-u) y1^T  [bf16]
//   x10: A <- A + V' + A@negE^T  (fp32 ACC in regs, bf16 A-shadow via LDS)
//   out1 = A_10 ; out2 = P - k Piy1 q^T
// R1 restructure (latency-bound gemmEV: MFMA 3%, HBM 19%, occ 15%):
//   - gemmEV: BK 32->128 (2 chunks), issue-all-loads-first staging (MLP 16),
//     XOR-swizzled LDS (reg-staged both sides), cross-chunk prefetch.
//   - prep2: BK 32->64 (8 chunks), all-loads-first fp32 staging + prefetch, swizzle.
//   - prep1: 512 blocks (32-row strips), loads issued up front. qpart 8 chunks.
//   - out2 tail moved from gemmEV into iterk's grid (overlaps compute).

#define BSZ 64
#define DD 256
#define MM 512

typedef __attribute__((ext_vector_type(8))) short short8;
typedef __attribute__((ext_vector_type(4))) float f32x4;

__device__ __forceinline__ unsigned short f2b(float f) {
    unsigned int u = __float_as_uint(f);
    unsigned int r = (u + 0x7fffu + ((u >> 16) & 1u)) >> 16;
    return (unsigned short)r;
}
__device__ __forceinline__ float b2f(unsigned short s) {
    return __uint_as_float(((unsigned int)s) << 16);
}

// vec per batch (768 f): [0,256) Piy1 | [256,512) q | [512] k

// ---------------- L1: P-conv + Piy1 + q-partials (512 blocks, 8/batch) ----------------
__global__ __launch_bounds__(256)
void prep1(const float* __restrict__ P, const float* __restrict__ y1g,
           unsigned short* __restrict__ Pb, float* __restrict__ vec,
           float* __restrict__ qpart)
{
    const int blk = blockIdx.x, t = threadIdx.x;
    const int b = blk >> 3, rs = (blk & 7) * 32;
    const long base = (long)b * DD * DD;
    const int wv = t >> 6, ln = t & 63;
    __shared__ float sy1[DD];
    __shared__ float qsh[4][DD];
    sy1[t] = y1g[b * DD + t];
    __syncthreads();
    const int col4 = ln * 4;
    const float4 yv = *(const float4*)(sy1 + col4);
    // issue all 8 row loads first (MLP 8)
    float4 pr[8];
#pragma unroll
    for (int i = 0; i < 8; ++i) {
        const int row = rs + i * 4 + wv;
        pr[i] = *(const float4*)(P + base + (long)row * DD + col4);
    }
    float ql0 = 0.f, ql1 = 0.f, ql2 = 0.f, ql3 = 0.f;
#pragma unroll
    for (int i = 0; i < 8; ++i) {
        const int row = rs + i * 4 + wv;          // all 64 lanes of wave share this row
        const long o = base + (long)row * DD + col4;
        const float4 p = pr[i];
        ushort4 u;
        u.x = f2b(p.x); u.y = f2b(p.y); u.z = f2b(p.z); u.w = f2b(p.w);
        *(ushort4*)(Pb + o) = u;
        const float yr = sy1[row];
        ql0 += yr * p.x; ql1 += yr * p.y; ql2 += yr * p.z; ql3 += yr * p.w;
        float s = p.x * yv.x + p.y * yv.y + p.z * yv.z + p.w * yv.w;   // Piy1 partial
#pragma unroll
        for (int off = 32; off; off >>= 1) s += __shfl_down(s, off, 64);
        if (ln == 0) vec[(long)b * 768 + row] = s;
    }
    *(float4*)(qsh[wv] + col4) = make_float4(ql0, ql1, ql2, ql3);
    __syncthreads();
    // per-block q partial over l in [rs, rs+32): qpart[(b*8 + strip)*256 + c]
    qpart[((long)blk) * DD + t] = qsh[0][t] + qsh[1][t] + qsh[2][t] + qsh[3][t];
}

// ---------------- L2: G-gemms (blocks 0..511, fp32 MLP staging) + finalize (512..575) --
__global__ __launch_bounds__(256)
void prep2(const float* __restrict__ Y1, const float* __restrict__ Y2,
           const float* __restrict__ y1g, const float* __restrict__ qpart,
           unsigned short* __restrict__ G1b, unsigned short* __restrict__ G21b,
           float* __restrict__ vec)
{
    __shared__ __align__(16) unsigned short As[128 * 64];   // 16 KB, swizzled
    __shared__ __align__(16) unsigned short Bs[128 * 64];
    const int blk = blockIdx.x, t = threadIdx.x;
    if (blk < 512) {
        const int quad = blk & 3, z = blk >> 2, sel = z >> 6, b = z & 63;
        const int i0 = (quad >> 1) * 128, j0 = (quad & 1) * 128;
        const float* Af = (sel ? Y2 : Y1) + (long)b * DD * MM;
        const float* Bf = Y1 + (long)b * DD * MM;
        unsigned short* Ob = (sel ? G21b : G1b) + (long)b * DD * DD;
        const int wv = t >> 6, ln = t & 63;
        const int lr = ln & 15, qd = ln >> 4;
        const int mh = (wv >> 1) * 64, nh = (wv & 1) * 64;
        const int srow = t >> 4, sc4 = t & 15;   // staging: row-within-16, float4 chunk
        f32x4 acc[4][4] = {};
        float4 fa[8], fb[8];

#define PRE2_ISSUE(kc)                                                          \
        _Pragma("unroll")                                                       \
        for (int i = 0; i < 8; ++i) {                                           \
            const int row = i * 16 + srow;                                      \
            fa[i] = *(const float4*)(Af + (long)(i0 + row) * MM + (kc) * 64 + sc4 * 4); \
            fb[i] = *(const float4*)(Bf + (long)(j0 + row) * MM + (kc) * 64 + sc4 * 4); \
        }

        PRE2_ISSUE(0);
        for (int kc = 0; kc < 8; ++kc) {
            // convert + swizzled store (consumes fa/fb; waits pipeline per-register)
#pragma unroll
            for (int i = 0; i < 8; ++i) {
                const int row = i * 16 + srow;
                const int cb = (sc4 * 8) ^ ((row & 7) << 4);    // byte col, 8B store
                ushort4 ua, ub;
                ua.x = f2b(fa[i].x); ua.y = f2b(fa[i].y); ua.z = f2b(fa[i].z); ua.w = f2b(fa[i].w);
                ub.x = f2b(fb[i].x); ub.y = f2b(fb[i].y); ub.z = f2b(fb[i].z); ub.w = f2b(fb[i].w);
                *(ushort4*)((char*)As + row * 128 + cb) = ua;
                *(ushort4*)((char*)Bs + row * 128 + cb) = ub;
            }
            __syncthreads();
            if (kc < 7) PRE2_ISSUE(kc + 1);     // prefetch next chunk under MFMA
#pragma unroll
            for (int kc2 = 0; kc2 < 2; ++kc2) {
                short8 af[4], bfr[4];
#pragma unroll
                for (int mt = 0; mt < 4; ++mt) {
                    const int row = mh + mt * 16 + lr;
                    af[mt] = *(const short8*)((char*)As + row * 128 +
                                              ((kc2 * 64 + qd * 16) ^ ((row & 7) << 4)));
                }
#pragma unroll
                for (int nt = 0; nt < 4; ++nt) {
                    const int row = nh + nt * 16 + lr;
                    bfr[nt] = *(const short8*)((char*)Bs + row * 128 +
                                               ((kc2 * 64 + qd * 16) ^ ((row & 7) << 4)));
                }
#pragma unroll
                for (int mt = 0; mt < 4; ++mt)
#pragma unroll
                    for (int nt = 0; nt < 4; ++nt)
                        acc[mt][nt] = __builtin_amdgcn_mfma_f32_16x16x32_bf16(
                            af[mt], bfr[nt], acc[mt][nt], 0, 0, 0);
            }
            __syncthreads();
        }
#undef PRE2_ISSUE
#pragma unroll
        for (int mt = 0; mt < 4; ++mt)
#pragma unroll
            for (int nt = 0; nt < 4; ++nt) {
                const int gr0 = i0 + mh + mt * 16 + qd * 4;
                const int gc  = j0 + nh + nt * 16 + lr;
#pragma unroll
                for (int r = 0; r < 4; ++r)
                    Ob[(long)(gr0 + r) * DD + gc] = f2b(acc[mt][nt][r]);
            }
        return;
    }
    // finalize: q = sum of 8 partials; k = 1/(1 + y1.Piy1)
    const int b = blk - 512;
    float* vb = vec + (long)b * 768;
    const float* qp = qpart + (long)b * 8 * DD;
    float qv = 0.f;
#pragma unroll
    for (int c = 0; c < 8; ++c) qv += qp[c * DD + t];
    vb[256 + t] = qv;
    __shared__ float red[256];
    red[t] = vb[t] * y1g[b * DD + t];
    __syncthreads();
    for (int s = 128; s; s >>= 1) { if (t < s) red[t] += red[t + s]; __syncthreads(); }
    if (t == 0) vb[512] = 1.0f / (1.0f + red[0]);
}

// ---------------- L3: negE (sel=0) / V' (sel=1), 512 blocks, BK=128 ----------------
__global__ __launch_bounds__(256)
void gemmEV(const unsigned short* __restrict__ Pb, const unsigned short* __restrict__ G1b,
            const unsigned short* __restrict__ G21b,
            const float* __restrict__ y1g, const float* __restrict__ y2g,
            const float* __restrict__ vec,
            unsigned short* __restrict__ Enb, unsigned short* __restrict__ Vpb)
{
    __shared__ __align__(16) unsigned short As[128 * 128];  // 32 KB, swizzled
    __shared__ __align__(16) unsigned short Bs[128 * 128];
    __shared__ float qs[DD], s1[DD], s2[DD];
    const int blk = blockIdx.x, t = threadIdx.x;
    const int quad = blk & 3, z = blk >> 2, sel = z >> 6, b = z & 63;
    const int i0 = (quad >> 1) * 128, j0 = (quad & 1) * 128;
    const unsigned short* Ab = (sel ? G21b : Pb) + (long)b * DD * DD;
    const unsigned short* Bb = (sel ? Pb : G1b) + (long)b * DD * DD;
    unsigned short* Ob = (sel ? Vpb : Enb) + (long)b * DD * DD;
    const float* vb = vec + (long)b * 768;
    const int wv = t >> 6, ln = t & 63;
    const int lr = ln & 15, qd = ln >> 4;
    const int mh = (wv >> 1) * 64, nh = (wv & 1) * 64;
    const int srow = t >> 4, sc16 = t & 15;   // staging: row-within-16, 16B chunk

    qs[t] = vb[256 + t];
    s1[t] = y1g[b * DD + t];
    s2[t] = y2g[b * DD + t];

    f32x4 acc[4][4] = {};
    float dot[4] = {0.f, 0.f, 0.f, 0.f};   // sel0: G1q partial per nt; sel1: G21q per mt
    uint4 ra[8], rb[8];

#define GEV_ISSUE(kc)                                                           \
    _Pragma("unroll")                                                           \
    for (int i = 0; i < 8; ++i) {                                               \
        const int row = i * 16 + srow;                                          \
        ra[i] = *(const uint4*)(Ab + (long)(i0 + row) * DD + (kc) * 128 + sc16 * 8); \
        rb[i] = *(const uint4*)(Bb + (long)(j0 + row) * DD + (kc) * 128 + sc16 * 8); \
    }

    GEV_ISSUE(0);
#pragma unroll
    for (int kc = 0; kc < 2; ++kc) {
#pragma unroll
        for (int i = 0; i < 8; ++i) {
            const int row = i * 16 + srow;
            const int cb = (sc16 * 16) ^ ((row & 7) << 4);    // byte col, 16B store
            *(uint4*)((char*)As + row * 256 + cb) = ra[i];
            *(uint4*)((char*)Bs + row * 256 + cb) = rb[i];
        }
        __syncthreads();
        if (kc == 0) GEV_ISSUE(1);            // prefetch chunk 1 under chunk 0 compute
#pragma unroll
        for (int kc2 = 0; kc2 < 4; ++kc2) {
            short8 af[4], bfr[4];
#pragma unroll
            for (int mt = 0; mt < 4; ++mt) {
                const int row = mh + mt * 16 + lr;
                af[mt] = *(const short8*)((char*)As + row * 256 +
                                          ((kc2 * 64 + qd * 16) ^ ((row & 7) << 4)));
            }
#pragma unroll
            for (int nt = 0; nt < 4; ++nt) {
                const int row = nh + nt * 16 + lr;
                bfr[nt] = *(const short8*)((char*)Bs + row * 256 +
                                           ((kc2 * 64 + qd * 16) ^ ((row & 7) << 4)));
            }
            const int kb = kc * 128 + kc2 * 32;
            const float4 qa = *(const float4*)(qs + kb + qd * 8);
            const float4 qb = *(const float4*)(qs + kb + qd * 8 + 4);
            const float qf[8] = {qa.x, qa.y, qa.z, qa.w, qb.x, qb.y, qb.z, qb.w};
            if (!sel) {
#pragma unroll
                for (int nt = 0; nt < 4; ++nt)
#pragma unroll
                    for (int j = 0; j < 8; ++j)
                        dot[nt] += b2f((unsigned short)bfr[nt][j]) * qf[j];
            } else {
#pragma unroll
                for (int mt = 0; mt < 4; ++mt)
#pragma unroll
                    for (int j = 0; j < 8; ++j)
                        dot[mt] += b2f((unsigned short)af[mt][j]) * qf[j];
            }
#pragma unroll
            for (int mt = 0; mt < 4; ++mt)
#pragma unroll
                for (int nt = 0; nt < 4; ++nt)
                    acc[mt][nt] = __builtin_amdgcn_mfma_f32_16x16x32_bf16(
                        af[mt], bfr[nt], acc[mt][nt], 0, 0, 0);
        }
        __syncthreads();
    }
#undef GEV_ISSUE
#pragma unroll
    for (int i = 0; i < 4; ++i) {
        dot[i] += __shfl_xor(dot[i], 16, 64);
        dot[i] += __shfl_xor(dot[i], 32, 64);
    }
    const float kk = vb[512];
#pragma unroll
    for (int mt = 0; mt < 4; ++mt) {
#pragma unroll
        for (int nt = 0; nt < 4; ++nt) {
            const int gr0 = i0 + mh + mt * 16 + qd * 4;
            const int gc  = j0 + nh + nt * 16 + lr;
            if (!sel) {
                const float cw = s1[gc] - dot[nt];   // w[col]
#pragma unroll
                for (int r = 0; r < 4; ++r) {
                    const float rv = kk * s1[gr0 + r];
                    Ob[(long)(gr0 + r) * DD + gc] = f2b(-(acc[mt][nt][r] + rv * cw));
                }
            } else {
                const float cv = s1[gc];
#pragma unroll
                for (int r = 0; r < 4; ++r) {
                    const float uv = __shfl(dot[mt], qd * 4 + r, 64);   // u[row]
                    const float rv = kk * (s2[gr0 + r] - uv);
                    Ob[(long)(gr0 + r) * DD + gc] = f2b(acc[mt][nt][r] + rv * cv);
                }
            }
        }
    }
}

// ---------------- L4: persistent 10-step iterate + out2 tail (512..767) ----------------
// blocks 0..511: 32-row strips, 2 WG/CU. Wave wv owns cols [wv*64, wv*64+64).
#define SWZ(row) (((row) ^ ((row) >> 3)) & 7)
__global__ __launch_bounds__(256, 2)
void iterk(const float* __restrict__ A_start, const unsigned short* __restrict__ Enb,
           const unsigned short* __restrict__ Vpb,
           const float* __restrict__ P, const float* __restrict__ vec,
           float* __restrict__ out1, float* __restrict__ out2)
{
    const int blk = blockIdx.x, t = threadIdx.x;
    if (blk >= 512) {
        // out2 = P - k Piy1 q^T  (pure BW; overlaps the compute-bound iterate blocks)
        const int c = blk - 512, b = c >> 2, rs = (c & 3) * 64;
        const long base = (long)b * DD * DD;
        const float* vb = vec + (long)b * 768;
        const float kk = vb[512];
#pragma unroll 4
        for (int i = 0; i < 16; ++i) {
            const int idx = rs * DD + (i * 256 + t) * 4;
            const int row = idx >> 8, col = idx & 255;
            const float kPi = kk * vb[row];
            float4 p = *(const float4*)(P + base + idx);
            float4 q = *(const float4*)(vb + 256 + col);
            float4 rr;
            rr.x = p.x - kPi * q.x; rr.y = p.y - kPi * q.y;
            rr.z = p.z - kPi * q.z; rr.w = p.w - kPi * q.w;
            *(float4*)(out2 + base + idx) = rr;
        }
        return;
    }
    __shared__ __align__(16) unsigned short Ash[32 * 256];
    const int b = blk >> 3, r0 = (blk & 7) * 32;
    const long base = (long)b * DD * DD;
    const float* Ab = A_start + base;
    const unsigned short* Eb = Enb + base;
    const unsigned short* Vb = Vpb + base;
    float* Ob = out1 + base;
    const int wv = t >> 6, ln = t & 63;
    const int lr = ln & 15, qd = ln >> 4;

    f32x4 acc[2][4], vv[2][4];
    short8 ef[4][8];

#pragma unroll
    for (int mt = 0; mt < 2; ++mt)
#pragma unroll
        for (int j = 0; j < 4; ++j) {
            const int col = wv * 64 + j * 16 + lr;
            const int rowb = r0 + mt * 16 + qd * 4;
#pragma unroll
            for (int r = 0; r < 4; ++r) {
                const long o = (long)(rowb + r) * DD + col;
                acc[mt][j][r] = Ab[o];
                vv[mt][j][r]  = b2f(Vb[o]);
            }
        }
#pragma unroll
    for (int j = 0; j < 4; ++j) {
        const int n = wv * 64 + j * 16 + lr;
#pragma unroll
        for (int kc = 0; kc < 8; ++kc)
            ef[j][kc] = *(const short8*)(Eb + (long)n * DD + kc * 32 + qd * 8);
    }

#pragma unroll 1
    for (int s = 0; s < 10; ++s) {
        const int cgb = wv * 8 + (lr >> 3), cb = lr & 7;
#pragma unroll
        for (int mt = 0; mt < 2; ++mt)
#pragma unroll
            for (int j = 0; j < 4; ++j) {
#pragma unroll
                for (int r = 0; r < 4; ++r) {
                    const int lrow = mt * 16 + qd * 4 + r;
                    const int cg = (cgb + j * 2) ^ SWZ(lrow);
                    Ash[lrow * 256 + cg * 8 + cb] = f2b(acc[mt][j][r]);
                }
                acc[mt][j] += vv[mt][j];
            }
        __syncthreads();
#pragma unroll
        for (int kc = 0; kc < 8; ++kc) {
            short8 af[2];
#pragma unroll
            for (int mt = 0; mt < 2; ++mt) {
                const int row = mt * 16 + lr;
                const int cg = (kc * 4 + qd) ^ SWZ(row);
                af[mt] = *(const short8*)(Ash + row * 256 + cg * 8);
            }
#pragma unroll
            for (int mt = 0; mt < 2; ++mt)
#pragma unroll
                for (int j = 0; j < 4; ++j)
                    acc[mt][j] = __builtin_amdgcn_mfma_f32_16x16x32_bf16(
                        af[mt], ef[j][kc], acc[mt][j], 0, 0, 0);
        }
        __syncthreads();
    }

#pragma unroll
    for (int mt = 0; mt < 2; ++mt)
#pragma unroll
        for (int j = 0; j < 4; ++j) {
            const int col = wv * 64 + j * 16 + lr;
            const int rowb = r0 + mt * 16 + qd * 4;
#pragma unroll
            for (int r = 0; r < 4; ++r)
                Ob[(long)(rowb + r) * DD + col] = acc[mt][j][r];
        }
}

extern "C" void kernel_launch(void* const* d_in, const int* in_sizes, int n_in,
                              void* d_out, int out_size, void* d_ws, size_t ws_size,
                              hipStream_t stream)
{
    const float* A_start = (const float*)d_in[0];
    const float* Y1      = (const float*)d_in[1];
    const float* Y2      = (const float*)d_in[2];
    const float* y1      = (const float*)d_in[3];
    const float* y2      = (const float*)d_in[4];
    const float* P       = (const float*)d_in[5];

    const long EL2 = (long)BSZ * DD * DD;   // 4,194,304

    float* out1 = (float*)d_out;
    float* out2 = out1 + EL2;

    char* w8 = (char*)d_ws;                          // ~42.7 MB used
    unsigned short* Pb    = (unsigned short*)(w8);                 // 8MB
    unsigned short* G1b   = (unsigned short*)(w8 + 8388608);       // 8MB
    unsigned short* G21b  = (unsigned short*)(w8 + 16777216);      // 8MB
    unsigned short* Enb   = (unsigned short*)(w8 + 25165824);      // 8MB
    unsigned short* Vpb   = (unsigned short*)(w8 + 33554432);      // 8MB
    float*          vec   = (float*)(w8 + 41943040);               // 64*768*4
    float*          qpart = (float*)(w8 + 42139648);               // 64*8*256*4

    const dim3 blk(256);

    prep1<<<512, blk, 0, stream>>>(P, y1, Pb, vec, qpart);
    prep2<<<576, blk, 0, stream>>>(Y1, Y2, y1, qpart, G1b, G21b, vec);
    gemmEV<<<512, blk, 0, stream>>>(Pb, G1b, G21b, y1, y2, vec, Enb, Vpb);
    iterk<<<768, blk, 0, stream>>>(A_start, Enb, Vpb, P, vec, out1, out2);
}

// Round 2
// 213.516 us; speedup vs baseline: 1.0556x; 1.0556x over previous
//
#include <hip/hip_runtime.h>
#include <hip/hip_bf16.h>
#include <stdint.h>

// DelayedDMD: BS=64, D=256, M=512, m_prox=10 (fixed). A-orientation algebra:
//   G1 = Y1@Y1^T (sym), G21 = Y2@Y1^T
//   q = P^T y1, Piy1 = P y1, k = 1/(1+y1.Piy1)
//   w = y1 - G1 q ; u = G21 q
//   negE = -(P@G1 + k y1 w^T)  [bf16]
//   V'   = G21@P^T + k (y2-u) y1^T  [bf16]
//   x10: A <- A + V' + A@negE^T  (fp32 ACC in regs, bf16 A-shadow via LDS)
//   out1 = A_10 ; out2 = P - k Piy1 q^T
// R2: R1's reg-staged prefetch SPILLED (67MB scratch writes in gemmEV = exact
// ra/rb footprint). Fixes:
//   - gemmEV/prep2 staging via __builtin_amdgcn_global_load_lds (no data regs),
//     swizzle applied on the GLOBAL source address, linear LDS dest, swizzled
//     ds_read (rule #21: src perm == read perm). Double-buffered, BK=64.
//   - Y1/Y2 -> bf16 pre-convert folded into prep1's grid; prep2 reads bf16
//     panels and fuses sel (G1+G21 share B-panel) -> ~2.7x less prep2 traffic.
//   - XCD-aware block swizzle (b -> XCD) in prep2/gemmEV/iterk so same-batch
//     panel re-reads (E: 8x/batch in iterk!) hit the per-XCD L2.

#define BSZ 64
#define DD 256
#define MM 512

typedef __attribute__((ext_vector_type(8))) short short8;
typedef __attribute__((ext_vector_type(4))) float f32x4;

__device__ __forceinline__ unsigned short f2b(float f) {
    unsigned int u = __float_as_uint(f);
    unsigned int r = (u + 0x7fffu + ((u >> 16) & 1u)) >> 16;
    return (unsigned short)r;
}
__device__ __forceinline__ float b2f(unsigned short s) {
    return __uint_as_float(((unsigned int)s) << 16);
}
// HBM -> LDS direct, 16B per lane. LDS dest must be wave-uniform base + lane*16.
__device__ __forceinline__ void gll16(const void* g, void* l) {
    __builtin_amdgcn_global_load_lds(
        (const __attribute__((address_space(1))) unsigned int*)g,
        (__attribute__((address_space(3))) unsigned int*)l, 16, 0, 0);
}

// vec per batch (768 f): [0,256) Piy1 | [256,512) q | [512] k

// ---- L1: P-conv + Piy1 + q-partials (blocks 0..511) + Y->bf16 conv (512..1535) ----
__global__ __launch_bounds__(256)
void prep1c(const float* __restrict__ P, const float* __restrict__ y1g,
            const float* __restrict__ Y1, const float* __restrict__ Y2,
            unsigned short* __restrict__ Pb, unsigned short* __restrict__ Y1b,
            unsigned short* __restrict__ Y2b,
            float* __restrict__ vec, float* __restrict__ qpart)
{
    const int blk = blockIdx.x, t = threadIdx.x;
    if (blk >= 512) {
        // streaming fp32 -> bf16 convert of Y1 (512 blocks) then Y2 (512 blocks)
        const int c = blk - 512;
        const float* src = (c < 512) ? Y1 : Y2;
        unsigned short* dst = (c < 512) ? Y1b : Y2b;
        const long base = (long)(c & 511) * 16384;
#pragma unroll 4
        for (int i = 0; i < 16; ++i) {
            const long idx = base + (long)(i * 256 + t) * 4;
            const float4 v = *(const float4*)(src + idx);
            ushort4 u;
            u.x = f2b(v.x); u.y = f2b(v.y); u.z = f2b(v.z); u.w = f2b(v.w);
            *(ushort4*)(dst + idx) = u;
        }
        return;
    }
    const int b = blk >> 3, rs = (blk & 7) * 32;
    const long base = (long)b * DD * DD;
    const int wv = t >> 6, ln = t & 63;
    __shared__ float sy1[DD];
    __shared__ float qsh[4][DD];
    sy1[t] = y1g[b * DD + t];
    __syncthreads();
    const int col4 = ln * 4;
    const float4 yv = *(const float4*)(sy1 + col4);
    float4 pr[8];
#pragma unroll
    for (int i = 0; i < 8; ++i) {
        const int row = rs + i * 4 + wv;
        pr[i] = *(const float4*)(P + base + (long)row * DD + col4);
    }
    float ql0 = 0.f, ql1 = 0.f, ql2 = 0.f, ql3 = 0.f;
#pragma unroll
    for (int i = 0; i < 8; ++i) {
        const int row = rs + i * 4 + wv;          // all 64 lanes of wave share this row
        const long o = base + (long)row * DD + col4;
        const float4 p = pr[i];
        ushort4 u;
        u.x = f2b(p.x); u.y = f2b(p.y); u.z = f2b(p.z); u.w = f2b(p.w);
        *(ushort4*)(Pb + o) = u;
        const float yr = sy1[row];
        ql0 += yr * p.x; ql1 += yr * p.y; ql2 += yr * p.z; ql3 += yr * p.w;
        float s = p.x * yv.x + p.y * yv.y + p.z * yv.z + p.w * yv.w;   // Piy1 partial
#pragma unroll
        for (int off = 32; off; off >>= 1) s += __shfl_down(s, off, 64);
        if (ln == 0) vec[(long)b * 768 + row] = s;
    }
    *(float4*)(qsh[wv] + col4) = make_float4(ql0, ql1, ql2, ql3);
    __syncthreads();
    qpart[((long)blk) * DD + t] = qsh[0][t] + qsh[1][t] + qsh[2][t] + qsh[3][t];
}

// ---- L2: fused G1+G21 gemms (blocks 0..255, bf16 panels, gload_lds) + finalize ----
__global__ __launch_bounds__(256)
void prep2(const unsigned short* __restrict__ Y1b, const unsigned short* __restrict__ Y2b,
           const float* __restrict__ y1g, const float* __restrict__ qpart,
           unsigned short* __restrict__ G1b, unsigned short* __restrict__ G21b,
           float* __restrict__ vec)
{
    const int blk = blockIdx.x, t = threadIdx.x;
    if (blk >= 256) {
        // finalize: q = sum of 8 partials; k = 1/(1 + y1.Piy1)
        const int b = blk - 256;
        float* vb = vec + (long)b * 768;
        const float* qp = qpart + (long)b * 8 * DD;
        float qv = 0.f;
#pragma unroll
        for (int c = 0; c < 8; ++c) qv += qp[c * DD + t];
        vb[256 + t] = qv;
        __shared__ float red[256];
        red[t] = vb[t] * y1g[b * DD + t];
        __syncthreads();
        for (int s = 128; s; s >>= 1) { if (t < s) red[t] += red[t + s]; __syncthreads(); }
        if (t == 0) vb[512] = 1.0f / (1.0f + red[0]);
        return;
    }
    __shared__ __align__(16) unsigned short S[2][3][128 * 64];   // 96 KB, dbuf x {Y1A,Y2A,BY}
    // XCD swizzle: same-b blocks land on one XCD -> Y panels L2-hit
    const int b = (blk & 7) + 8 * (blk >> 5), quad = (blk >> 3) & 3;
    const int i0 = (quad >> 1) * 128, j0 = (quad & 1) * 128;
    const char* A1 = (const char*)(Y1b + (long)b * DD * MM + (long)i0 * MM);
    const char* A2 = (const char*)(Y2b + (long)b * DD * MM + (long)i0 * MM);
    const char* By = (const char*)(Y1b + (long)b * DD * MM + (long)j0 * MM);
    const int wv = t >> 6, ln = t & 63;
    const int lr = ln & 15, qd = ln >> 4;
    const int mh = (wv >> 1) * 64, nh = (wv & 1) * 64;
    const int srow = t >> 3;           // staging row-within-32
    const int sc = (t & 7) * 16;       // byte chunk in 128B (BK=64) row
    f32x4 acc1[4][4] = {}, acc2[4][4] = {};

    // source col pre-swizzled; LDS linear (lane*16); read applies same XOR
#define P2STAGE(u, kc)                                                            \
    _Pragma("unroll")                                                             \
    for (int i = 0; i < 4; ++i) {                                                 \
        const int row = i * 32 + srow;                                            \
        const int gco = (kc) * 128 + (sc ^ ((row & 7) << 4));                     \
        const int lo = row * 128 + sc;                                            \
        gll16(A1 + (long)row * 1024 + gco, (char*)S[u][0] + lo);                  \
        gll16(A2 + (long)row * 1024 + gco, (char*)S[u][1] + lo);                  \
        gll16(By + (long)row * 1024 + gco, (char*)S[u][2] + lo);                  \
    }

    P2STAGE(0, 0);
    for (int kc = 0; kc < 8; ++kc) {
        __syncthreads();                         // drains chunk kc's loads
        if (kc < 7) { P2STAGE((kc + 1) & 1, kc + 1); }
        const unsigned short (*Su)[128 * 64] = S[kc & 1];
#pragma unroll
        for (int kc2 = 0; kc2 < 2; ++kc2) {
            const int kb = kc2 * 64 + qd * 16;
            short8 a1[4], a2[4], bf[4];
#pragma unroll
            for (int mt = 0; mt < 4; ++mt) {
                const int row = mh + mt * 16 + lr;
                const int o = row * 128 + (kb ^ ((row & 7) << 4));
                a1[mt] = *(const short8*)((const char*)Su[0] + o);
                a2[mt] = *(const short8*)((const char*)Su[1] + o);
            }
#pragma unroll
            for (int nt = 0; nt < 4; ++nt) {
                const int row = nh + nt * 16 + lr;
                bf[nt] = *(const short8*)((const char*)Su[2] + row * 128 +
                                          (kb ^ ((row & 7) << 4)));
            }
#pragma unroll
            for (int mt = 0; mt < 4; ++mt)
#pragma unroll
                for (int nt = 0; nt < 4; ++nt) {
                    acc1[mt][nt] = __builtin_amdgcn_mfma_f32_16x16x32_bf16(
                        a1[mt], bf[nt], acc1[mt][nt], 0, 0, 0);
                    acc2[mt][nt] = __builtin_amdgcn_mfma_f32_16x16x32_bf16(
                        a2[mt], bf[nt], acc2[mt][nt], 0, 0, 0);
                }
        }
    }
#undef P2STAGE
    unsigned short* O1 = G1b  + (long)b * DD * DD;
    unsigned short* O2 = G21b + (long)b * DD * DD;
#pragma unroll
    for (int mt = 0; mt < 4; ++mt)
#pragma unroll
        for (int nt = 0; nt < 4; ++nt) {
            const int gr0 = i0 + mh + mt * 16 + qd * 4;
            const int gc  = j0 + nh + nt * 16 + lr;
#pragma unroll
            for (int r = 0; r < 4; ++r) {
                O1[(long)(gr0 + r) * DD + gc] = f2b(acc1[mt][nt][r]);
                O2[(long)(gr0 + r) * DD + gc] = f2b(acc2[mt][nt][r]);
            }
        }
}

// ---- L3: negE (sel=0) / V' (sel=1), 512 blocks, BK=64, gload_lds + dbuf ----
__global__ __launch_bounds__(256)
void gemmEV(const unsigned short* __restrict__ Pb, const unsigned short* __restrict__ G1b,
            const unsigned short* __restrict__ G21b,
            const float* __restrict__ y1g, const float* __restrict__ y2g,
            const float* __restrict__ vec,
            unsigned short* __restrict__ Enb, unsigned short* __restrict__ Vpb)
{
    __shared__ __align__(16) unsigned short S[2][2][128 * 64];   // 64 KB
    __shared__ float qs[DD], s1[DD], s2[DD];
    const int blk = blockIdx.x, t = threadIdx.x;
    // XCD swizzle: 8 blocks of a batch share one XCD's L2
    const int b = (blk & 7) + 8 * (blk >> 6);
    const int rem = (blk >> 3) & 7, sel = rem >> 2, quad = rem & 3;
    const int i0 = (quad >> 1) * 128, j0 = (quad & 1) * 128;
    const char* Ab = (const char*)((sel ? G21b : Pb) + (long)b * DD * DD + (long)i0 * DD);
    const char* Bb = (const char*)((sel ? Pb : G1b) + (long)b * DD * DD + (long)j0 * DD);
    unsigned short* Ob = (sel ? Vpb : Enb) + (long)b * DD * DD;
    const float* vb = vec + (long)b * 768;
    const int wv = t >> 6, ln = t & 63;
    const int lr = ln & 15, qd = ln >> 4;
    const int mh = (wv >> 1) * 64, nh = (wv & 1) * 64;
    const int srow = t >> 3;
    const int sc = (t & 7) * 16;

    qs[t] = vb[256 + t];
    s1[t] = y1g[b * DD + t];
    s2[t] = y2g[b * DD + t];

    f32x4 acc[4][4] = {};
    float dot[4] = {0.f, 0.f, 0.f, 0.f};   // sel0: G1q partial per nt; sel1: G21q per mt

#define GEVSTAGE(u, kc)                                                           \
    _Pragma("unroll")                                                             \
    for (int i = 0; i < 4; ++i) {                                                 \
        const int row = i * 32 + srow;                                            \
        const int gco = (kc) * 128 + (sc ^ ((row & 7) << 4));                     \
        const int lo = row * 128 + sc;                                            \
        gll16(Ab + (long)row * 512 + gco, (char*)S[u][0] + lo);                   \
        gll16(Bb + (long)row * 512 + gco, (char*)S[u][1] + lo);                   \
    }

    GEVSTAGE(0, 0);
    for (int kc = 0; kc < 4; ++kc) {
        __syncthreads();
        if (kc < 3) { GEVSTAGE((kc + 1) & 1, kc + 1); }
        const unsigned short (*Su)[128 * 64] = S[kc & 1];
#pragma unroll
        for (int kc2 = 0; kc2 < 2; ++kc2) {
            const int kb = kc2 * 64 + qd * 16;   // byte offset within 128B row
            short8 af[4], bfr[4];
#pragma unroll
            for (int mt = 0; mt < 4; ++mt) {
                const int row = mh + mt * 16 + lr;
                af[mt] = *(const short8*)((const char*)Su[0] + row * 128 +
                                          (kb ^ ((row & 7) << 4)));
            }
#pragma unroll
            for (int nt = 0; nt < 4; ++nt) {
                const int row = nh + nt * 16 + lr;
                bfr[nt] = *(const short8*)((const char*)Su[1] + row * 128 +
                                           (kb ^ ((row & 7) << 4)));
            }
            const int kel = kc * 64 + kc2 * 32 + qd * 8;   // element k of this frag
            const float4 qa = *(const float4*)(qs + kel);
            const float4 qb = *(const float4*)(qs + kel + 4);
            const float qf[8] = {qa.x, qa.y, qa.z, qa.w, qb.x, qb.y, qb.z, qb.w};
            if (!sel) {
#pragma unroll
                for (int nt = 0; nt < 4; ++nt)
#pragma unroll
                    for (int j = 0; j < 8; ++j)
                        dot[nt] += b2f((unsigned short)bfr[nt][j]) * qf[j];
            } else {
#pragma unroll
                for (int mt = 0; mt < 4; ++mt)
#pragma unroll
                    for (int j = 0; j < 8; ++j)
                        dot[mt] += b2f((unsigned short)af[mt][j]) * qf[j];
            }
#pragma unroll
            for (int mt = 0; mt < 4; ++mt)
#pragma unroll
                for (int nt = 0; nt < 4; ++nt)
                    acc[mt][nt] = __builtin_amdgcn_mfma_f32_16x16x32_bf16(
                        af[mt], bfr[nt], acc[mt][nt], 0, 0, 0);
        }
    }
#undef GEVSTAGE
#pragma unroll
    for (int i = 0; i < 4; ++i) {
        dot[i] += __shfl_xor(dot[i], 16, 64);
        dot[i] += __shfl_xor(dot[i], 32, 64);
    }
    const float kk = vb[512];
#pragma unroll
    for (int mt = 0; mt < 4; ++mt) {
#pragma unroll
        for (int nt = 0; nt < 4; ++nt) {
            const int gr0 = i0 + mh + mt * 16 + qd * 4;
            const int gc  = j0 + nh + nt * 16 + lr;
            if (!sel) {
                const float cw = s1[gc] - dot[nt];   // w[col]
#pragma unroll
                for (int r = 0; r < 4; ++r) {
                    const float rv = kk * s1[gr0 + r];
                    Ob[(long)(gr0 + r) * DD + gc] = f2b(-(acc[mt][nt][r] + rv * cw));
                }
            } else {
                const float cv = s1[gc];
#pragma unroll
                for (int r = 0; r < 4; ++r) {
                    const float uv = __shfl(dot[mt], qd * 4 + r, 64);   // u[row]
                    const float rv = kk * (s2[gr0 + r] - uv);
                    Ob[(long)(gr0 + r) * DD + gc] = f2b(acc[mt][nt][r] + rv * cv);
                }
            }
        }
    }
}

// ---- L4: persistent 10-step iterate (0..511, XCD-swizzled) + out2 tail (512..767) ----
#define SWZ(row) (((row) ^ ((row) >> 3)) & 7)
__global__ __launch_bounds__(256, 2)
void iterk(const float* __restrict__ A_start, const unsigned short* __restrict__ Enb,
           const unsigned short* __restrict__ Vpb,
           const float* __restrict__ P, const float* __restrict__ vec,
           float* __restrict__ out1, float* __restrict__ out2)
{
    const int blk = blockIdx.x, t = threadIdx.x;
    if (blk >= 512) {
        // out2 = P - k Piy1 q^T  (pure BW; overlaps the compute-bound iterate blocks)
        const int c = blk - 512, b = c >> 2, rs = (c & 3) * 64;
        const long base = (long)b * DD * DD;
        const float* vb = vec + (long)b * 768;
        const float kk = vb[512];
#pragma unroll 4
        for (int i = 0; i < 16; ++i) {
            const int idx = rs * DD + (i * 256 + t) * 4;
            const int row = idx >> 8, col = idx & 255;
            const float kPi = kk * vb[row];
            float4 p = *(const float4*)(P + base + idx);
            float4 q = *(const float4*)(vb + 256 + col);
            float4 rr;
            rr.x = p.x - kPi * q.x; rr.y = p.y - kPi * q.y;
            rr.z = p.z - kPi * q.z; rr.w = p.w - kPi * q.w;
            *(float4*)(out2 + base + idx) = rr;
        }
        return;
    }
    __shared__ __align__(16) unsigned short Ash[32 * 256];
    // XCD swizzle: 8 strip-blocks of a batch share one XCD -> E/V panels L2-hit
    const int b = (blk & 7) + 8 * (blk >> 6), r0 = ((blk >> 3) & 7) * 32;
    const long base = (long)b * DD * DD;
    const float* Ab = A_start + base;
    const unsigned short* Eb = Enb + base;
    const unsigned short* Vb = Vpb + base;
    float* Ob = out1 + base;
    const int wv = t >> 6, ln = t & 63;
    const int lr = ln & 15, qd = ln >> 4;

    f32x4 acc[2][4], vv[2][4];
    short8 ef[4][8];

#pragma unroll
    for (int mt = 0; mt < 2; ++mt)
#pragma unroll
        for (int j = 0; j < 4; ++j) {
            const int col = wv * 64 + j * 16 + lr;
            const int rowb = r0 + mt * 16 + qd * 4;
#pragma unroll
            for (int r = 0; r < 4; ++r) {
                const long o = (long)(rowb + r) * DD + col;
                acc[mt][j][r] = Ab[o];
                vv[mt][j][r]  = b2f(Vb[o]);
            }
        }
#pragma unroll
    for (int j = 0; j < 4; ++j) {
        const int n = wv * 64 + j * 16 + lr;
#pragma unroll
        for (int kc = 0; kc < 8; ++kc)
            ef[j][kc] = *(const short8*)(Eb + (long)n * DD + kc * 32 + qd * 8);
    }

#pragma unroll 1
    for (int s = 0; s < 10; ++s) {
        const int cgb = wv * 8 + (lr >> 3), cb = lr & 7;
#pragma unroll
        for (int mt = 0; mt < 2; ++mt)
#pragma unroll
            for (int j = 0; j < 4; ++j) {
#pragma unroll
                for (int r = 0; r < 4; ++r) {
                    const int lrow = mt * 16 + qd * 4 + r;
                    const int cg = (cgb + j * 2) ^ SWZ(lrow);
                    Ash[lrow * 256 + cg * 8 + cb] = f2b(acc[mt][j][r]);
                }
                acc[mt][j] += vv[mt][j];
            }
        __syncthreads();
#pragma unroll
        for (int kc = 0; kc < 8; ++kc) {
            short8 af[2];
#pragma unroll
            for (int mt = 0; mt < 2; ++mt) {
                const int row = mt * 16 + lr;
                const int cg = (kc * 4 + qd) ^ SWZ(row);
                af[mt] = *(const short8*)(Ash + row * 256 + cg * 8);
            }
#pragma unroll
            for (int mt = 0; mt < 2; ++mt)
#pragma unroll
                for (int j = 0; j < 4; ++j)
                    acc[mt][j] = __builtin_amdgcn_mfma_f32_16x16x32_bf16(
                        af[mt], ef[j][kc], acc[mt][j], 0, 0, 0);
        }
        __syncthreads();
    }

#pragma unroll
    for (int mt = 0; mt < 2; ++mt)
#pragma unroll
        for (int j = 0; j < 4; ++j) {
            const int col = wv * 64 + j * 16 + lr;
            const int rowb = r0 + mt * 16 + qd * 4;
#pragma unroll
            for (int r = 0; r < 4; ++r)
                Ob[(long)(rowb + r) * DD + col] = acc[mt][j][r];
        }
}

extern "C" void kernel_launch(void* const* d_in, const int* in_sizes, int n_in,
                              void* d_out, int out_size, void* d_ws, size_t ws_size,
                              hipStream_t stream)
{
    const float* A_start = (const float*)d_in[0];
    const float* Y1      = (const float*)d_in[1];
    const float* Y2      = (const float*)d_in[2];
    const float* y1      = (const float*)d_in[3];
    const float* y2      = (const float*)d_in[4];
    const float* P       = (const float*)d_in[5];

    const long EL2 = (long)BSZ * DD * DD;   // 4,194,304

    float* out1 = (float*)d_out;
    float* out2 = out1 + EL2;

    char* w8 = (char*)d_ws;                          // ~76.2 MB used
    unsigned short* Pb    = (unsigned short*)(w8);                 // 8MB
    unsigned short* G1b   = (unsigned short*)(w8 + 8388608);       // 8MB
    unsigned short* G21b  = (unsigned short*)(w8 + 16777216);      // 8MB
    unsigned short* Enb   = (unsigned short*)(w8 + 25165824);      // 8MB
    unsigned short* Vpb   = (unsigned short*)(w8 + 33554432);      // 8MB
    unsigned short* Y1b   = (unsigned short*)(w8 + 41943040);      // 16MB
    unsigned short* Y2b   = (unsigned short*)(w8 + 58720256);      // 16MB
    float*          vec   = (float*)(w8 + 75497472);               // 64*768*4
    float*          qpart = (float*)(w8 + 75694080);               // 64*8*256*4

    const dim3 blk(256);

    prep1c<<<1536, blk, 0, stream>>>(P, y1, Y1, Y2, Pb, Y1b, Y2b, vec, qpart);
    prep2<<<320, blk, 0, stream>>>(Y1b, Y2b, y1, qpart, G1b, G21b, vec);
    gemmEV<<<512, blk, 0, stream>>>(Pb, G1b, G21b, y1, y2, vec, Enb, Vpb);
    iterk<<<768, blk, 0, stream>>>(A_start, Enb, Vpb, P, vec, out1, out2);
}